// Round 2
// baseline (78.915 us; speedup 1.0000x reference)
//
#include <hip/hip_runtime.h>

// ShardedEmbedIn: out[b,s,:] = W[ids[b,s],:]
// One-hot fp16 matmul == exact row gather. Harness stores fp16 arrays
// upcast to FLOAT32 on device (evidence: npz sizes 729/118 MB = f32 raw
// x0.588; raw-copy experiment produced bounded error 0.165 = wrong-row
// f32 values, not garbage exponents). So: f32 in, f32 out, pure row copy.
//
// B=4, S=2048, V=50432, H=6144. Row = 6144 f32 = 1536 uint4 (16B).

#define HIDDEN 6144
#define VEC_PER_ROW (HIDDEN / 4)   // 1536 uint4 per row (4 f32 each)

__global__ __launch_bounds__(256) void embed_gather_f32_kernel(
    const int* __restrict__ ids,
    const uint4* __restrict__ W,
    uint4* __restrict__ out,
    int n_tokens)
{
    const int token = blockIdx.x;
    if (token >= n_tokens) return;
    const int id = ids[token];  // wave-uniform -> scalar broadcast
    const uint4* __restrict__ src = W + (size_t)id * VEC_PER_ROW;
    uint4* __restrict__ dst = out + (size_t)token * VEC_PER_ROW;
    // 1536 vecs / 256 threads = 6 fully-coalesced 16B iterations
    #pragma unroll
    for (int i = 0; i < VEC_PER_ROW / 256; ++i) {
        const int idx = i * 256 + threadIdx.x;
        dst[idx] = src[idx];
    }
}

extern "C" void kernel_launch(void* const* d_in, const int* in_sizes, int n_in,
                              void* d_out, int out_size, void* d_ws, size_t ws_size,
                              hipStream_t stream) {
    const int* ids = (const int*)d_in[0];    // [B*S] int32
    const uint4* W = (const uint4*)d_in[1];  // [V, H] float32, viewed as uint4
    uint4* out = (uint4*)d_out;              // [B*S, H] float32, viewed as uint4

    const int n_tokens = in_sizes[0];        // 8192
    embed_gather_f32_kernel<<<n_tokens, 256, 0, stream>>>(ids, W, out, n_tokens);
}

// Round 4
// 63.898 us; speedup vs baseline: 1.2350x; 1.2350x over previous
//
#include <hip/hip_runtime.h>

// ShardedEmbedIn: out[b,s,:] = W[ids[b,s],:]  (one-hot fp16 matmul == row gather)
// f32 storage on device (verified round 2: absmax 0.0, 78.9 us = 5.1 TB/s).
// Round 4: same as round 3 but with native clang vector type so
// __builtin_nontemporal_store compiles (HIP_vector_type uint4 is a struct,
// the builtin needs a real vector).

typedef unsigned int u32x4 __attribute__((ext_vector_type(4)));  // 16B

#define HIDDEN 6144
#define VEC_PER_ROW (HIDDEN / 4)          // 1536 x 16B per row
#define ITERS (VEC_PER_ROW / 256)         // 6 per thread

__global__ __launch_bounds__(256) void embed_gather_f32_kernel(
    const int* __restrict__ ids,
    const u32x4* __restrict__ W,
    u32x4* __restrict__ out,
    int n_tokens)
{
    const int token = blockIdx.x;
    if (token >= n_tokens) return;
    const int id = ids[token];  // wave-uniform -> scalar broadcast
    const u32x4* __restrict__ src = W + (size_t)id * VEC_PER_ROW + threadIdx.x;
    u32x4* __restrict__ dst = out + (size_t)token * VEC_PER_ROW + threadIdx.x;

    u32x4 r[ITERS];
    #pragma unroll
    for (int i = 0; i < ITERS; ++i)
        r[i] = src[i * 256];              // 6 outstanding 16B loads
    #pragma unroll
    for (int i = 0; i < ITERS; ++i)
        __builtin_nontemporal_store(r[i], &dst[i * 256]);  // streaming store
}

extern "C" void kernel_launch(void* const* d_in, const int* in_sizes, int n_in,
                              void* d_out, int out_size, void* d_ws, size_t ws_size,
                              hipStream_t stream) {
    const int* ids = (const int*)d_in[0];      // [B*S] int32
    const u32x4* W = (const u32x4*)d_in[1];    // [V, H] float32, viewed as 16B vecs
    u32x4* out = (u32x4*)d_out;                // [B*S, H] float32, viewed as 16B vecs

    const int n_tokens = in_sizes[0];          // 8192
    embed_gather_f32_kernel<<<n_tokens, 256, 0, stream>>>(ids, W, out, n_tokens);
}